// Round 4
// baseline (12461.850 us; speedup 1.0000x reference)
//
#include <hip/hip_runtime.h>

// 2-layer LSTM (H=256, T=256, B=512, I=2) + linear head.
// 256 blocks x 512 threads (2 waves/SIMD), 2 batches/block, t-loop in-kernel.
// R22: fix R21's stream-order bug. R21 consumed gates2 frags in order
// {8 Wih2 ktiles, then Whh2 kt0} per rowtile but memory/prep order was
// {all 64 Wih2, then 8 Whh2} -> rotation slot phase broke at consumption
// 72 and every later consumption got a scrambled frag (observed absmax
// 1.85e-2 matches the predicted magnitude of this exact scramble).
// Fix: prep emits stream frags in consumption order (q=f-64; rt=q/9;
// pos=q%9; pos<8 -> Wih2 kt=pos, pos=8 -> Whh2 kt0), and kernel uses slot
// (rt*9+pos)&7 (compile-time). Invariant restored: consumption c uses
// buf[c&7] which holds frag c; 136 % 8 == 0 so pattern repeats per step.
// R21: MFMA offload. R20 analysis: step = port(~6.5us) + VALU(~3-6us) +
// serial, nearly additive (2 barrier-locked waves/SIMD can't hide compute
// under vmcnt waits). MfmaUtil was 0. All dot products now
// v_mfma_f32_16x16x32_f16 (2/16 B-cols real = 8x lane waste, but the pipe
// is idle). Same byte economy as R20: 136 x 16B stream loads/thread/step,
// 160 VGPR park regs (40 frags, Whh2 ktiles 1-5), 128KB LDS parks
// (ktiles 6-7), parks interleaved per-rowtile. A-frag: lane l holds
// row rt*16+(l&15), k = kt*32+(l>>4)*8..+7 (f16x8 = 16B). B-frag: lane
// reads h[lane&1][kt*32+(lane>>4)*8..+7] (broadcast; cols 2..15 garbage,
// discarded). C: col=lane&15, row=(lane>>4)*4+reg (m89-verified) -> lanes
// col<2 write 4 contig rows via 16B store. Bias/x-terms live in U1/U2 as
// per-thread reg constants (gemm writes RAW Whh1*h1 / Wih2*h1+Whh2*h2).
// Prediction: passes ~1e-4; dur ~2000-2300, VALUBusy ->20-30%, MfmaUtil
// ->8-15%, FETCH ~7.5e3 KB unchanged (spill detector; fallback NVPF 40->32).
// Kept: 2 lgkm-only barriers, h fp16 single-buffered in LDS, c in regs,
// y deferred 1 step. Round-3 lesson: no cross-block exchange.

typedef float vf2 __attribute__((ext_vector_type(2)));
typedef float v4f __attribute__((ext_vector_type(4)));
typedef _Float16 vh4 __attribute__((ext_vector_type(4)));
typedef _Float16 vh8 __attribute__((ext_vector_type(8)));

#define NT 512
#define TSTEPS 256
#define NSF 136           // streamed frags per wave per step (1KB each)
#define NVPF 40           // VGPR-parked frags per wave (Whh2 ktiles 1..5)
#define NLPF 16           // LDS-parked frags per wave  (Whh2 ktiles 6..7)
#define FRB 1024          // bytes per frag (64 lanes x 16B)
#define VPBASE (8 * NSF * FRB)            // 1088 KB
#define LPBASE (VPBASE + 8 * NVPF * FRB)  // 1408 KB
#define FS 393216         // fp32 table offset (floats) = 1536KB/4

__global__ void prep_kernel(const float* __restrict__ W_ih1,
                            const float* __restrict__ W_hh1,
                            const float* __restrict__ b_ih1,
                            const float* __restrict__ b_hh1,
                            const float* __restrict__ W_ih2,
                            const float* __restrict__ W_hh2,
                            const float* __restrict__ b_ih2,
                            const float* __restrict__ b_hh2,
                            void* __restrict__ ws) {
    const int stride = gridDim.x * blockDim.x;
    const int idx = blockIdx.x * blockDim.x + threadIdx.x;
    _Float16* wh = (_Float16*)ws;
    float* wf = (float*)ws;
    // A-fragment layout for v_mfma_f32_16x16x32_f16:
    //   frag (w, matrix m, rowtile rt, ktile kt): 1KB, halfword index
    //   within frag = lane*8 + j;  element = M[w*128 + rt*16 + (lane&15)]
    //                                         [kt*32 + (lane>>4)*8 + j].
    // STREAM ORDER == CONSUMPTION ORDER (R22 fix):
    //   kb<1088: stream, w=kb/136, f=kb%136:
    //     f<64:  gates1: Whh1 rt=f>>3, kt=f&7
    //     f>=64: gates2: q=f-64, rt=q/9, pos=q%9;
    //            pos<8 -> Wih2 rt kt=pos | pos==8 -> Whh2 rt kt=0
    // kb<1408: VGPR park, w=(kb-1088)/40, p=%40: Whh2 rt=p/5, kt=1+p%5
    // else:    LDS park,  w=(kb-1408)>>4, q=&15: Whh2 rt=q>>1, kt=6+(q&1)
    for (int e = idx; e < 786432; e += stride) {
        int kb = e >> 9;
        int lane = (e & 511) >> 3, jj = e & 7;
        int w, rt, kt, m;
        if (kb < 1088) {
            w = kb / 136; int f = kb % 136;
            if (f < 64) { m = 0; rt = f >> 3; kt = f & 7; }
            else {
                int q = f - 64; rt = q / 9; int pos = q % 9;
                if (pos < 8) { m = 1; kt = pos; }
                else         { m = 2; kt = 0; }
            }
        } else if (kb < 1408) {
            int k2 = kb - 1088; w = k2 / 40; int p = k2 % 40;
            m = 2; rt = p / 5; kt = 1 + p % 5;
        } else {
            int k3 = kb - 1408; w = k3 >> 4; int q = k3 & 15;
            m = 2; rt = q >> 1; kt = 6 + (q & 1);
        }
        int row = w * 128 + rt * 16 + (lane & 15);
        int k   = kt * 32 + ((lane >> 4) << 3) + jj;
        float v = (m == 0) ? W_hh1[row * 256 + k]
                : (m == 1) ? W_ih2[row * 256 + k]
                           : W_hh2[row * 256 + k];
        wh[e] = (_Float16)v;
    }
    for (int j = idx; j < 1024; j += stride) {
        wf[FS + j]        = W_ih1[j * 2 + 0];
        wf[FS + 1024 + j] = W_ih1[j * 2 + 1];
        wf[FS + 2048 + j] = b_ih1[j] + b_hh1[j];
        wf[FS + 3072 + j] = b_ih2[j] + b_hh2[j];
    }
}

__device__ __forceinline__ float sig_(float v) {
    return 1.f / (1.f + __expf(-v));
}
__device__ __forceinline__ float tanh_(float v) {
    return 1.f - 2.f / (__expf(2.f * v) + 1.f);
}
__device__ __forceinline__ v4f mfma16(vh8 a, vh8 b, v4f c) {
    return __builtin_amdgcn_mfma_f32_16x16x32_f16(a, b, c, 0, 0, 0);
}

// lgkm-only barrier: LDS drained, weight-stream vmem stays in flight.
#define BARRIER() __asm__ volatile("s_waitcnt lgkmcnt(0)\ns_barrier" ::: "memory")

__global__ __launch_bounds__(NT, 2) void lstm_kernel(
    const float* __restrict__ x,      // (512, 256, 2)
    const void* __restrict__ ws,
    const float* __restrict__ W_lin,  // (2, 256)
    const float* __restrict__ b_lin,  // (2,)
    float* __restrict__ out)          // (512, 256, 2)
{
    __shared__ float g1buf[2][1024];               // raw Whh1*h1 [batch][row]
    __shared__ float g2buf[2][1024];               // raw gates2 gemm
    __shared__ __align__(16) _Float16 h1s[2][256]; // h1 [batch][unit]
    __shared__ __align__(16) _Float16 h2s[2][256]; // h2
    __shared__ __align__(16) char lds_park[NLPF * 8 * FRB]; // 128 KB

    const int tid = threadIdx.x;
    const int lane = tid & 63, w = tid >> 6;       // wave id = rowgroup
    const int u = tid & 255, bu = tid >> 8;        // cell-update: unit, batch
    const int b0 = blockIdx.x * 2;
    const char* wstream = (const char*)ws;
    const float* wf = (const float*)ws;
    const int l16 = lane * 16;

    // U-stage affine constants: rows u, 256+u, 512+u, 768+u
    float wxa[4], wxb[4], b1c[4], b2c[4];
    #pragma unroll
    for (int g = 0; g < 4; ++g) {
        int r = g * 256 + u;
        wxa[g] = wf[FS + r];        wxb[g] = wf[FS + 1024 + r];
        b1c[g] = wf[FS + 2048 + r]; b2c[g] = wf[FS + 3072 + r];
    }

    // y-head: waves 0..3 -> (batch ob, output oo); lane covers 4 units
    const int ob = (w >> 1) & 1, oo = w & 1;
    const float wl0 = W_lin[oo * 256 + 4 * lane + 0];
    const float wl1 = W_lin[oo * 256 + 4 * lane + 1];
    const float wl2 = W_lin[oo * 256 + 4 * lane + 2];
    const float wl3 = W_lin[oo * 256 + 4 * lane + 3];
    const float blin = b_lin[oo];

    // zero initial h and g1buf (t=0: Whh1*h1(-1) = 0)
    ((_Float16*)h1s)[tid] = (_Float16)0.f;
    ((_Float16*)h2s)[tid] = (_Float16)0.f;
    g1buf[0][tid] = 0.f; g1buf[0][512 + tid] = 0.f;
    g1buf[1][tid] = 0.f; g1buf[1][512 + tid] = 0.f;

    float c1 = 0.f, c2 = 0.f;

    // stage LDS parks: lds[(q*8+w)*1024 + lane*16] <- ws[LPBASE+(w*16+q)*1024]
    for (int q = 0; q < NLPF; ++q) {
        *(vh8*)&lds_park[(((q << 3) + w) << 10) + l16] =
            *(const vh8*)(wstream + LPBASE + (((w << 4) + q) << 10) + l16);
    }

    // VGPR parks: 40 frags (Whh2 ktiles 1..5 x 8 rowtiles), PINNED.
    vh8 wreg[NVPF];
    #pragma unroll
    for (int p = 0; p < NVPF; ++p) {
        union { vh8 v; float f[4]; } tpk;
        tpk.v = *(const vh8*)(wstream + VPBASE + ((w * NVPF + p) << 10) + l16);
        asm volatile("" : "+v"(tpk.f[0]), "+v"(tpk.f[1]),
                          "+v"(tpk.f[2]), "+v"(tpk.f[3]));
        wreg[p] = tpk.v;
    }

    // stream: per-wave base, 8 rotating frag buffers, uniform sp.
    // Invariant: consumption c (per step, 0..135) uses buf[c&7] == frag c.
    const char* wbase = wstream + (size_t)w * (NSF * FRB);
    int sp = 0;
    vh8 buf[8];
    auto loadf = [&](int bi) {
        buf[bi] = *(const vh8*)(wbase + sp + l16);
        sp += FRB; if (sp == NSF * FRB) sp = 0;
    };
    #pragma unroll
    for (int i = 0; i < 8; ++i) loadf(i);

    // B-fragment from h LDS: col=lane&15 (only 0/1 real; garbage cols read
    // batch lane&1 - finite, discarded). k = kt*32 + (lane>>4)*8 .. +7.
    auto bfrag = [&](const _Float16 (*hp)[256], int kt) -> vh8 {
        return *(const vh8*)&hp[lane & 1][kt * 32 + ((lane >> 4) << 3)];
    };

    const int bx = b0 + bu;
    vf2 xv = *(const vf2*)(x + (size_t)bx * 512);   // x(0)

    __syncthreads();   // init barrier (full drain once is fine)

    #pragma unroll 1
    for (int t = 0; t < TSTEPS; ++t) {
        // ---- U1: gates1(t) = g1buf(raw) + b1 + Wih1*x(t) -> h1(t) ----
        {
            float p0 = g1buf[bu][u]       + b1c[0] + wxa[0] * xv.x + wxb[0] * xv.y;
            float p1 = g1buf[bu][256 + u] + b1c[1] + wxa[1] * xv.x + wxb[1] * xv.y;
            float p2 = g1buf[bu][512 + u] + b1c[2] + wxa[2] * xv.x + wxb[2] * xv.y;
            float p3 = g1buf[bu][768 + u] + b1c[3] + wxa[3] * xv.x + wxb[3] * xv.y;
            c1 = sig_(p1) * c1 + sig_(p0) * tanh_(p2);
            h1s[bu][u] = (_Float16)(sig_(p3) * tanh_(c1));
        }
        {   // prefetch x(t+1) (wraps harmlessly)
            const int tn = (t + 1) & (TSTEPS - 1);
            xv = *(const vf2*)(x + (size_t)bx * 512 + tn * 2);
        }
        BARRIER();   // B1: h1(t) visible; h2(t-1) (from prev U2) visible

        // ---- y(t-1) (deferred; h2(t-1) stable in this epoch) ----
        if (t > 0 && w < 4) {
            vh4 hv = *(const vh4*)&h2s[ob][4 * lane];
            float s = (float)hv.x * wl0 + (float)hv.y * wl1
                    + (float)hv.z * wl2 + (float)hv.w * wl3;
            #pragma unroll
            for (int m = 32; m >= 1; m >>= 1) s += __shfl_xor(s, m, 64);
            if (lane == 0)
                out[(size_t)(b0 + ob) * 512 + (t - 1) * 2 + oo] = s + blin;
        }

        // ---- gates1(t+1) raw = Whh1 * h1(t)  [consumptions 0..63] ----
        #pragma unroll
        for (int rt = 0; rt < 8; ++rt) {
            v4f acc = {0.f, 0.f, 0.f, 0.f};
            #pragma unroll
            for (int kt = 0; kt < 8; ++kt) {
                const int sl = kt;                  // (rt*8+kt)&7
                vh8 B = bfrag(h1s, kt);
                acc = mfma16(buf[sl], B, acc);
                loadf(sl);
            }
            if ((lane & 15) < 2)
                *(v4f*)&g1buf[lane & 15][w * 128 + rt * 16 + ((lane >> 4) << 2)] = acc;
        }

        // ---- gates2(t) raw = Wih2*h1(t) + Whh2*h2(t-1)
        //      [consumptions 64..135: per rt {8 Wih2 ktiles, Whh2 kt0};
        //       kt1..5 VGPR parks, kt6..7 LDS parks, interleaved per rt] ----
        #pragma unroll
        for (int rt = 0; rt < 8; ++rt) {
            v4f acc = {0.f, 0.f, 0.f, 0.f};
            #pragma unroll
            for (int kt = 0; kt < 8; ++kt) {
                const int sl = (rt * 9 + kt) & 7;   // consumption-order slot
                vh8 B = bfrag(h1s, kt);
                acc = mfma16(buf[sl], B, acc);
                loadf(sl);
            }
            {   // Whh2 ktile 0 streamed; refill wraps into next step's frags
                const int sl = (rt * 9 + 8) & 7;
                vh8 B = bfrag(h2s, 0);
                acc = mfma16(buf[sl], B, acc);
                loadf(sl);
            }
            #pragma unroll
            for (int kk = 1; kk <= 5; ++kk)
                acc = mfma16(wreg[rt * 5 + (kk - 1)], bfrag(h2s, kk), acc);
            #pragma unroll
            for (int kk = 6; kk <= 7; ++kk) {
                vh8 A = *(const vh8*)
                    &lds_park[((((rt * 2 + (kk - 6)) << 3) + w) << 10) + l16];
                acc = mfma16(A, bfrag(h2s, kk), acc);
            }
            if ((lane & 15) < 2)
                *(v4f*)&g2buf[lane & 15][w * 128 + rt * 16 + ((lane >> 4) << 2)] = acc;
        }
        BARRIER();   // B2: g1buf/g2buf visible

        // ---- U2: gates2 + b2 -> h2(t) ----
        {
            float q0 = g2buf[bu][u]       + b2c[0];
            float q1 = g2buf[bu][256 + u] + b2c[1];
            float q2 = g2buf[bu][512 + u] + b2c[2];
            float q3 = g2buf[bu][768 + u] + b2c[3];
            c2 = sig_(q1) * c2 + sig_(q0) * tanh_(q2);
            h2s[bu][u] = (_Float16)(sig_(q3) * tanh_(c2));
        }
        // no barrier: next iteration's B1 publishes h2(t) before it's read
    }

    // ---- tail: y(255) ----
    BARRIER();
    if (w < 4) {
        vh4 hv = *(const vh4*)&h2s[ob][4 * lane];
        float s = (float)hv.x * wl0 + (float)hv.y * wl1
                + (float)hv.z * wl2 + (float)hv.w * wl3;
        #pragma unroll
        for (int m = 32; m >= 1; m >>= 1) s += __shfl_xor(s, m, 64);
        if (lane == 0)
            out[(size_t)(b0 + ob) * 512 + 255 * 2 + oo] = s + blin;
    }
}

extern "C" void kernel_launch(void* const* d_in, const int* in_sizes, int n_in,
                              void* d_out, int out_size, void* d_ws, size_t ws_size,
                              hipStream_t stream) {
    const float* x     = (const float*)d_in[0];
    const float* W_ih1 = (const float*)d_in[1];
    const float* W_hh1 = (const float*)d_in[2];
    const float* b_ih1 = (const float*)d_in[3];
    const float* b_hh1 = (const float*)d_in[4];
    const float* W_ih2 = (const float*)d_in[5];
    const float* W_hh2 = (const float*)d_in[6];
    const float* b_ih2 = (const float*)d_in[7];
    const float* b_hh2 = (const float*)d_in[8];
    const float* W_lin = (const float*)d_in[9];
    const float* b_lin = (const float*)d_in[10];
    float* out = (float*)d_out;

    prep_kernel<<<256, 256, 0, stream>>>(W_ih1, W_hh1, b_ih1, b_hh1,
                                         W_ih2, W_hh2, b_ih2, b_hh2, d_ws);
    lstm_kernel<<<256, NT, 0, stream>>>(x, d_ws, W_lin, b_lin, out);
}

// Round 5
// 3367.582 us; speedup vs baseline: 3.7005x; 3.7005x over previous
//
#include <hip/hip_runtime.h>

// 2-layer LSTM (H=256, T=256, B=512, I=2) + linear head.
// 256 blocks x 512 threads (2 waves/SIMD), 2 batches/block, t-loop in-kernel.
// R23: MFMA offload + ROLLED structure. R22 passed correctness (frag
// layouts HW-verified) but fully-unrolled gemm bodies spilled the pinned
// parks to scratch (FETCH 22.8GB ~= 40 frags x 16B x thr x steps reload;
// R7-R10 lesson: big unrolled schedules spill). R23 restores R20's rolled
// discipline: Stream A (Whh1 64 + Wih2 64 frags/wave, 8 named bufs,
// slot==kt uniform per rt -> rolled rt loops). Stream B (Whh2 kt0,
// 8 frags/wave, E0/E1 alternating). gates2 split two-pass: 2a rolled
// (Wih2 partial -> g2buf), 2b unrolled-small (reload partial; streamB +
// 5 VGPR parks static-idx + 2 LDS parks; store final). Same byte economy:
// 136 x 16B stream loads/thread/step, 160 park regs, 128KB LDS parks.
// All dots via v_mfma_f32_16x16x32_f16 (2/16 cols real; pipe was idle;
// R20 showed port + VALU nearly additive with 2 barrier-locked waves).
// Prediction: FETCH ~7.5e3 KB (spill gone - primary check), dur
// ~2100-2400us, MfmaUtil 10-18%, VALUBusy 15-25%. Fallback: NVPF 40->32.
// A-frag: lane holds row rt*16+(l&15), k=kt*32+(l>>4)*8..+7 (HW-verified
// R22). B-frag: h[lane&1][kt*32+(l>>4)*8..+7] (cols 2..15 garbage,
// discarded). C: col=l&15, row=(l>>4)*4+reg -> lanes col<2 store v4f.
// Bias/x-terms in U1/U2 as per-thread reg constants (gemm writes RAW).
// Kept: 2 lgkm-only barriers, h fp16 single-buffered in LDS, c in regs,
// y deferred 1 step. Round-3 lesson: no cross-block exchange.

typedef float vf2 __attribute__((ext_vector_type(2)));
typedef float v4f __attribute__((ext_vector_type(4)));
typedef _Float16 vh4 __attribute__((ext_vector_type(4)));
typedef _Float16 vh8 __attribute__((ext_vector_type(8)));

#define NT 512
#define TSTEPS 256
#define NSA 128           // stream-A frags per wave per step (1KB each)
#define NSB 8             // stream-B frags per wave per step
#define NVPF 40           // VGPR-parked frags per wave (Whh2 ktiles 1..5)
#define NLPF 16           // LDS-parked frags per wave  (Whh2 ktiles 6..7)
#define FRB 1024          // bytes per frag (64 lanes x 16B)
#define SBBASE (1024 * FRB)               // 1024 KB
#define VPBASE (1088 * FRB)               // 1088 KB
#define LPBASE (1408 * FRB)               // 1408 KB
#define FS 393216         // fp32 table offset (floats) = 1536KB/4

__global__ void prep_kernel(const float* __restrict__ W_ih1,
                            const float* __restrict__ W_hh1,
                            const float* __restrict__ b_ih1,
                            const float* __restrict__ b_hh1,
                            const float* __restrict__ W_ih2,
                            const float* __restrict__ W_hh2,
                            const float* __restrict__ b_ih2,
                            const float* __restrict__ b_hh2,
                            void* __restrict__ ws) {
    const int stride = gridDim.x * blockDim.x;
    const int idx = blockIdx.x * blockDim.x + threadIdx.x;
    _Float16* wh = (_Float16*)ws;
    float* wf = (float*)ws;
    // A-fragment layout for v_mfma_f32_16x16x32_f16 (HW-verified R22):
    //   frag (w, matrix m, rowtile rt, ktile kt): 1KB, halfword index
    //   within frag = lane*8 + j;  element = M[w*128 + rt*16 + (lane&15)]
    //                                         [kt*32 + (lane>>4)*8 + j].
    // Frag index kb = e>>9:
    //   kb<1024: stream A, w=kb>>7, f=kb&127:
    //     f<64 -> Whh1 rt=f>>3 kt=f&7 | f>=64 -> Wih2 rt=(f>>3)&7 kt=f&7
    //   kb<1088: stream B, w=(kb-1024)>>3, rt=kb&7, Whh2 kt=0
    //   kb<1408: VGPR park, w=(kb-1088)/40, p=%40: Whh2 rt=p/5, kt=1+p%5
    //   else:    LDS park,  w=(kb-1408)>>4, q=&15: Whh2 rt=q>>1, kt=6+(q&1)
    for (int e = idx; e < 786432; e += stride) {
        int kb = e >> 9;
        int lane = (e & 511) >> 3, jj = e & 7;
        int w, rt, kt, m;
        if (kb < 1024) {
            w = kb >> 7; int f = kb & 127;
            if (f < 64) { m = 0; rt = f >> 3;       kt = f & 7; }
            else        { m = 1; rt = (f >> 3) & 7; kt = f & 7; }
        } else if (kb < 1088) {
            int k1 = kb - 1024; w = k1 >> 3; m = 2; rt = k1 & 7; kt = 0;
        } else if (kb < 1408) {
            int k2 = kb - 1088; w = k2 / 40; int p = k2 % 40;
            m = 2; rt = p / 5; kt = 1 + p % 5;
        } else {
            int k3 = kb - 1408; w = k3 >> 4; int q = k3 & 15;
            m = 2; rt = q >> 1; kt = 6 + (q & 1);
        }
        int row = w * 128 + rt * 16 + (lane & 15);
        int k   = kt * 32 + ((lane >> 4) << 3) + jj;
        float v = (m == 0) ? W_hh1[row * 256 + k]
                : (m == 1) ? W_ih2[row * 256 + k]
                           : W_hh2[row * 256 + k];
        wh[e] = (_Float16)v;
    }
    for (int j = idx; j < 1024; j += stride) {
        wf[FS + j]        = W_ih1[j * 2 + 0];
        wf[FS + 1024 + j] = W_ih1[j * 2 + 1];
        wf[FS + 2048 + j] = b_ih1[j] + b_hh1[j];
        wf[FS + 3072 + j] = b_ih2[j] + b_hh2[j];
    }
}

__device__ __forceinline__ float sig_(float v) {
    return 1.f / (1.f + __expf(-v));
}
__device__ __forceinline__ float tanh_(float v) {
    return 1.f - 2.f / (__expf(2.f * v) + 1.f);
}
__device__ __forceinline__ v4f mfma16(vh8 a, vh8 b, v4f c) {
    return __builtin_amdgcn_mfma_f32_16x16x32_f16(a, b, c, 0, 0, 0);
}

// lgkm-only barrier: LDS drained, weight-stream vmem stays in flight.
#define BARRIER() __asm__ volatile("s_waitcnt lgkmcnt(0)\ns_barrier" ::: "memory")

__global__ __launch_bounds__(NT, 2) void lstm_kernel(
    const float* __restrict__ x,      // (512, 256, 2)
    const void* __restrict__ ws,
    const float* __restrict__ W_lin,  // (2, 256)
    const float* __restrict__ b_lin,  // (2,)
    float* __restrict__ out)          // (512, 256, 2)
{
    __shared__ float g1buf[2][1024];               // raw Whh1*h1 [batch][row]
    __shared__ float g2buf[2][1024];               // gates2 gemm (partial/final)
    __shared__ __align__(16) _Float16 h1s[2][256]; // h1 [batch][unit]
    __shared__ __align__(16) _Float16 h2s[2][256]; // h2
    __shared__ __align__(16) char lds_park[NLPF * 8 * FRB]; // 128 KB

    const int tid = threadIdx.x;
    const int lane = tid & 63, w = tid >> 6;       // wave id = rowgroup
    const int u = tid & 255, bu = tid >> 8;        // cell-update: unit, batch
    const int b0 = blockIdx.x * 2;
    const char* wstream = (const char*)ws;
    const float* wf = (const float*)ws;
    const int l16 = lane * 16;

    // U-stage affine constants: rows u, 256+u, 512+u, 768+u
    float wxa[4], wxb[4], b1c[4], b2c[4];
    #pragma unroll
    for (int g = 0; g < 4; ++g) {
        int r = g * 256 + u;
        wxa[g] = wf[FS + r];        wxb[g] = wf[FS + 1024 + r];
        b1c[g] = wf[FS + 2048 + r]; b2c[g] = wf[FS + 3072 + r];
    }

    // y-head: waves 0..3 -> (batch ob, output oo); lane covers 4 units
    const int ob = (w >> 1) & 1, oo = w & 1;
    const float wl0 = W_lin[oo * 256 + 4 * lane + 0];
    const float wl1 = W_lin[oo * 256 + 4 * lane + 1];
    const float wl2 = W_lin[oo * 256 + 4 * lane + 2];
    const float wl3 = W_lin[oo * 256 + 4 * lane + 3];
    const float blin = b_lin[oo];

    // zero initial h and g1buf (t=0: Whh1*h1(-1) = 0)
    ((_Float16*)h1s)[tid] = (_Float16)0.f;
    ((_Float16*)h2s)[tid] = (_Float16)0.f;
    g1buf[0][tid] = 0.f; g1buf[0][512 + tid] = 0.f;
    g1buf[1][tid] = 0.f; g1buf[1][512 + tid] = 0.f;

    float c1 = 0.f, c2 = 0.f;

    // stage LDS parks: lds[(q*8+w)*1024 + l16] <- ws[LPBASE+(w*16+q)*1024+l16]
    for (int q = 0; q < NLPF; ++q) {
        *(vh8*)&lds_park[(((q << 3) + w) << 10) + l16] =
            *(const vh8*)(wstream + LPBASE + (((w << 4) + q) << 10) + l16);
    }

    // VGPR parks: 40 frags (Whh2 ktiles 1..5 x 8 rowtiles), PINNED.
    vh8 wreg[NVPF];
    #pragma unroll
    for (int p = 0; p < NVPF; ++p) {
        union { vh8 v; float f[4]; } tpk;
        tpk.v = *(const vh8*)(wstream + VPBASE + ((w * NVPF + p) << 10) + l16);
        asm volatile("" : "+v"(tpk.f[0]), "+v"(tpk.f[1]),
                          "+v"(tpk.f[2]), "+v"(tpk.f[3]));
        wreg[p] = tpk.v;
    }

    // streams: per-wave bases, named rotating buffers, uniform pointers.
    // Invariant A: consumption c (0..127 per step) uses slot c&7 == frag c.
    // Invariant B: consumption rt uses E[rt&1] == frag rt.
    const char* wbaseA = wstream + (size_t)w * (NSA * FRB);
    const char* wbaseB = wstream + SBBASE + (size_t)w * (NSB * FRB);
    int spA = 0, spB = 0;
    vh8 B0, B1, B2, B3, B4, B5, B6, B7, E0, E1;
    auto LDA = [&](vh8& d) {
        d = *(const vh8*)(wbaseA + spA + l16);
        spA += FRB; if (spA == NSA * FRB) spA = 0;
    };
    auto LDB = [&](vh8& d) {
        d = *(const vh8*)(wbaseB + spB + l16);
        spB += FRB; if (spB == NSB * FRB) spB = 0;
    };
    LDA(B0); LDA(B1); LDA(B2); LDA(B3);
    LDA(B4); LDA(B5); LDA(B6); LDA(B7);
    LDB(E0); LDB(E1);

    // B-fragment from h LDS: col=lane&15 (only 0/1 real; garbage cols read
    // batch lane&1 - finite, discarded). k = kt*32 + (lane>>4)*8 .. +7.
    auto bfrag = [&](const _Float16 (*hp)[256], int kt) -> vh8 {
        return *(const vh8*)&hp[lane & 1][kt * 32 + ((lane >> 4) << 3)];
    };

    const int bx = b0 + bu;
    vf2 xv = *(const vf2*)(x + (size_t)bx * 512);   // x(0)

    __syncthreads();   // init barrier (full drain once is fine)

    #pragma unroll 1
    for (int t = 0; t < TSTEPS; ++t) {
        // ---- U1: gates1(t) = g1buf(raw) + b1 + Wih1*x(t) -> h1(t) ----
        {
            float p0 = g1buf[bu][u]       + b1c[0] + wxa[0] * xv.x + wxb[0] * xv.y;
            float p1 = g1buf[bu][256 + u] + b1c[1] + wxa[1] * xv.x + wxb[1] * xv.y;
            float p2 = g1buf[bu][512 + u] + b1c[2] + wxa[2] * xv.x + wxb[2] * xv.y;
            float p3 = g1buf[bu][768 + u] + b1c[3] + wxa[3] * xv.x + wxb[3] * xv.y;
            c1 = sig_(p1) * c1 + sig_(p0) * tanh_(p2);
            h1s[bu][u] = (_Float16)(sig_(p3) * tanh_(c1));
        }
        {   // prefetch x(t+1) (wraps harmlessly)
            const int tn = (t + 1) & (TSTEPS - 1);
            xv = *(const vf2*)(x + (size_t)bx * 512 + tn * 2);
        }
        BARRIER();   // B1: h1(t) visible; h2(t-1) (from prev U2) visible

        // ---- y(t-1) (deferred; h2(t-1) stable in this epoch) ----
        if (t > 0 && w < 4) {
            vh4 hv = *(const vh4*)&h2s[ob][4 * lane];
            float s = (float)hv.x * wl0 + (float)hv.y * wl1
                    + (float)hv.z * wl2 + (float)hv.w * wl3;
            #pragma unroll
            for (int m = 32; m >= 1; m >>= 1) s += __shfl_xor(s, m, 64);
            if (lane == 0)
                out[(size_t)(b0 + ob) * 512 + (t - 1) * 2 + oo] = s + blin;
        }

        // ---- gates1(t+1) raw = Whh1 * h1(t)  [stream A frags 0..63] ----
        #pragma unroll 1
        for (int rt = 0; rt < 8; ++rt) {
            v4f acc = {0.f, 0.f, 0.f, 0.f};
            acc = mfma16(B0, bfrag(h1s, 0), acc); LDA(B0);
            acc = mfma16(B1, bfrag(h1s, 1), acc); LDA(B1);
            acc = mfma16(B2, bfrag(h1s, 2), acc); LDA(B2);
            acc = mfma16(B3, bfrag(h1s, 3), acc); LDA(B3);
            acc = mfma16(B4, bfrag(h1s, 4), acc); LDA(B4);
            acc = mfma16(B5, bfrag(h1s, 5), acc); LDA(B5);
            acc = mfma16(B6, bfrag(h1s, 6), acc); LDA(B6);
            acc = mfma16(B7, bfrag(h1s, 7), acc); LDA(B7);
            if ((lane & 15) < 2)
                *(v4f*)&g1buf[lane & 15][w * 128 + rt * 16 + ((lane >> 4) << 2)] = acc;
        }

        // ---- gates2 pass 2a: partial = Wih2 * h1(t)  [stream A 64..127] ----
        #pragma unroll 1
        for (int rt = 0; rt < 8; ++rt) {
            v4f acc = {0.f, 0.f, 0.f, 0.f};
            acc = mfma16(B0, bfrag(h1s, 0), acc); LDA(B0);
            acc = mfma16(B1, bfrag(h1s, 1), acc); LDA(B1);
            acc = mfma16(B2, bfrag(h1s, 2), acc); LDA(B2);
            acc = mfma16(B3, bfrag(h1s, 3), acc); LDA(B3);
            acc = mfma16(B4, bfrag(h1s, 4), acc); LDA(B4);
            acc = mfma16(B5, bfrag(h1s, 5), acc); LDA(B5);
            acc = mfma16(B6, bfrag(h1s, 6), acc); LDA(B6);
            acc = mfma16(B7, bfrag(h1s, 7), acc); LDA(B7);
            if ((lane & 15) < 2)
                *(v4f*)&g2buf[lane & 15][w * 128 + rt * 16 + ((lane >> 4) << 2)] = acc;
        }
        // (B0..B7 now hold next step's gates1 frags; stream A wrapped.)

        // ---- gates2 pass 2b: += Whh2 * h2(t-1)  [streamB kt0 + parks] ----
        // Unrolled-small (64 MFMA): static park indices; same-thread LDS
        // RAW on g2buf partial (compiler orders via lgkmcnt, no barrier).
        #pragma unroll
        for (int rt = 0; rt < 8; ++rt) {
            v4f acc = {0.f, 0.f, 0.f, 0.f};
            if ((lane & 15) < 2)
                acc = *(const v4f*)&g2buf[lane & 15][w * 128 + rt * 16 + ((lane >> 4) << 2)];
            if (rt & 1) { acc = mfma16(E1, bfrag(h2s, 0), acc); LDB(E1); }
            else        { acc = mfma16(E0, bfrag(h2s, 0), acc); LDB(E0); }
            acc = mfma16(wreg[rt * 5 + 0], bfrag(h2s, 1), acc);
            acc = mfma16(wreg[rt * 5 + 1], bfrag(h2s, 2), acc);
            acc = mfma16(wreg[rt * 5 + 2], bfrag(h2s, 3), acc);
            acc = mfma16(wreg[rt * 5 + 3], bfrag(h2s, 4), acc);
            acc = mfma16(wreg[rt * 5 + 4], bfrag(h2s, 5), acc);
            {
                vh8 A6 = *(const vh8*)
                    &lds_park[((((rt * 2 + 0) << 3) + w) << 10) + l16];
                acc = mfma16(A6, bfrag(h2s, 6), acc);
            }
            {
                vh8 A7 = *(const vh8*)
                    &lds_park[((((rt * 2 + 1) << 3) + w) << 10) + l16];
                acc = mfma16(A7, bfrag(h2s, 7), acc);
            }
            if ((lane & 15) < 2)
                *(v4f*)&g2buf[lane & 15][w * 128 + rt * 16 + ((lane >> 4) << 2)] = acc;
        }
        BARRIER();   // B2: g1buf/g2buf visible

        // ---- U2: gates2 + b2 -> h2(t) ----
        {
            float q0 = g2buf[bu][u]       + b2c[0];
            float q1 = g2buf[bu][256 + u] + b2c[1];
            float q2 = g2buf[bu][512 + u] + b2c[2];
            float q3 = g2buf[bu][768 + u] + b2c[3];
            c2 = sig_(q1) * c2 + sig_(q0) * tanh_(q2);
            h2s[bu][u] = (_Float16)(sig_(q3) * tanh_(c2));
        }
        // no barrier: next iteration's B1 publishes h2(t) before it's read
    }

    // ---- tail: y(255) ----
    BARRIER();
    if (w < 4) {
        vh4 hv = *(const vh4*)&h2s[ob][4 * lane];
        float s = (float)hv.x * wl0 + (float)hv.y * wl1
                + (float)hv.z * wl2 + (float)hv.w * wl3;
        #pragma unroll
        for (int m = 32; m >= 1; m >>= 1) s += __shfl_xor(s, m, 64);
        if (lane == 0)
            out[(size_t)(b0 + ob) * 512 + 255 * 2 + oo] = s + blin;
    }
}

extern "C" void kernel_launch(void* const* d_in, const int* in_sizes, int n_in,
                              void* d_out, int out_size, void* d_ws, size_t ws_size,
                              hipStream_t stream) {
    const float* x     = (const float*)d_in[0];
    const float* W_ih1 = (const float*)d_in[1];
    const float* W_hh1 = (const float*)d_in[2];
    const float* b_ih1 = (const float*)d_in[3];
    const float* b_hh1 = (const float*)d_in[4];
    const float* W_ih2 = (const float*)d_in[5];
    const float* W_hh2 = (const float*)d_in[6];
    const float* b_ih2 = (const float*)d_in[7];
    const float* b_hh2 = (const float*)d_in[8];
    const float* W_lin = (const float*)d_in[9];
    const float* b_lin = (const float*)d_in[10];
    float* out = (float*)d_out;

    prep_kernel<<<256, 256, 0, stream>>>(W_ih1, W_hh1, b_ih1, b_hh1,
                                         W_ih2, W_hh2, b_ih2, b_hh2, d_ws);
    lstm_kernel<<<256, NT, 0, stream>>>(x, d_ws, W_lin, b_lin, out);
}

// Round 6
// 2705.349 us; speedup vs baseline: 4.6064x; 1.2448x over previous
//
#include <hip/hip_runtime.h>

// 2-layer LSTM (H=256, T=256, B=512, I=2) + linear head.
// 256 blocks x 512 threads (2 waves/SIMD), 2 batches/block, t-loop in-kernel.
// R24: MFMA offload, R23's four stall sources removed. R23 counters:
// offload engaged (VALU 57->15%, Mfma 0->20%) but dur 2826->3368 from
// (1) scratch leak (WRITE 30MB) + 5% L2 miss (FETCH 117MB): ~246 regs too
// close to 256 cap; (2) 1e8 bank conflicts (= count of bfrag reads, 2-way,
// ~4%); (3) stream-B depth-2 (E0/E1) stalls; (4) pass-2b draws ~nothing
// from the port (B0..7 full) -> port idle. Fix: ONE stream in consumption
// order, 144 frags/wave/step = 0 mod 8: [64 Whh1][64 Wih2][8 x (kt0,kt5)
// pairs]. Depth-8 everywhere, pass 2b pulls 16KB/wave, NVPF 40->32
// (kt1..4 parked; kt5 streamed) -> ~225 regs peak. Slot phase compile-time
// (rolled loops slot=kt; p2b unrolled slots (2rt)&7,(2rt+1)&7 via macro).
// Roofline: per-XCD L2 BW 4.3TB/s -> floor 32CU x 1152KB / 4.3TB/s =
// 8.6us/step. Prediction: FETCH ~8-15MB WRITE ~2.5MB (primary check;
// >50MB -> NVPF 24 fallback), dur ~2500-2750, Mfma 18-25%, VALU 15-20%.
// A-frag (HW-verified R22/R23): lane holds row rt*16+(l&15),
// k=kt*32+(l>>4)*8..+7. B-frag: h[lane&1][kt*32+(l>>4)*8..+7] (cols 2..15
// garbage, discarded). C: col=l&15, row=(l>>4)*4+reg; lanes col<2 store.
// Bias/x in U1/U2 as reg constants (gemm writes RAW sums).
// Kept: 2 lgkm-only barriers, h fp16 single-buffered LDS, c in regs,
// y deferred 1 step, 128KB LDS parks (kt6,7), rolled streaming loops
// (R7-R10/R22: big unrolled schedules spill). No cross-block exchange.

typedef float vf2 __attribute__((ext_vector_type(2)));
typedef float v4f __attribute__((ext_vector_type(4)));
typedef _Float16 vh4 __attribute__((ext_vector_type(4)));
typedef _Float16 vh8 __attribute__((ext_vector_type(8)));

#define NT 512
#define TSTEPS 256
#define NSF 144           // streamed frags per wave per step (1KB each)
#define NVPF 32           // VGPR-parked frags per wave (Whh2 ktiles 1..4)
#define NLPF 16           // LDS-parked frags per wave  (Whh2 ktiles 6..7)
#define FRB 1024          // bytes per frag (64 lanes x 16B)
#define VPBASE (1152 * FRB)               // 8 waves x 144 frags
#define LPBASE (1408 * FRB)               // 1152 + 8x32
#define FS 393216         // fp32 table offset (floats) = 1536KB/4

__global__ void prep_kernel(const float* __restrict__ W_ih1,
                            const float* __restrict__ W_hh1,
                            const float* __restrict__ b_ih1,
                            const float* __restrict__ b_hh1,
                            const float* __restrict__ W_ih2,
                            const float* __restrict__ W_hh2,
                            const float* __restrict__ b_ih2,
                            const float* __restrict__ b_hh2,
                            void* __restrict__ ws) {
    const int stride = gridDim.x * blockDim.x;
    const int idx = blockIdx.x * blockDim.x + threadIdx.x;
    _Float16* wh = (_Float16*)ws;
    float* wf = (float*)ws;
    // A-fragment layout (HW-verified): frag = 1KB; halfword index within
    // frag = lane*8 + j; element = M[w*128 + rt*16 + (lane&15)]
    //                               [kt*32 + (lane>>4)*8 + j].
    // Frag index kb = e>>9 (stream region in CONSUMPTION order):
    //   kb<1152: stream, w=kb/144, f=kb%144:
    //     f<64  -> Whh1 rt=f>>3, kt=f&7
    //     f<128 -> Wih2 rt=(f-64)>>3, kt=f&7
    //     else  -> q=f-128: Whh2 rt=q>>1, kt=(q&1)?5:0
    //   kb<1408: VGPR park, p2=kb-1152: w=p2>>5, p=p2&31:
    //            Whh2 rt=p>>2, kt=1+(p&3)
    //   else:    LDS park, k3=kb-1408: w=k3>>4, q=k3&15:
    //            Whh2 rt=q>>1, kt=6+(q&1)
    for (int e = idx; e < 786432; e += stride) {
        int kb = e >> 9;
        int lane = (e & 511) >> 3, jj = e & 7;
        int w, rt, kt, m;
        if (kb < 1152) {
            w = kb / 144; int f = kb % 144;
            if (f < 64)       { m = 0; rt = f >> 3;        kt = f & 7; }
            else if (f < 128) { m = 1; rt = (f - 64) >> 3; kt = f & 7; }
            else { int q = f - 128; m = 2; rt = q >> 1; kt = (q & 1) ? 5 : 0; }
        } else if (kb < 1408) {
            int p2 = kb - 1152; w = p2 >> 5; int p = p2 & 31;
            m = 2; rt = p >> 2; kt = 1 + (p & 3);
        } else {
            int k3 = kb - 1408; w = k3 >> 4; int q = k3 & 15;
            m = 2; rt = q >> 1; kt = 6 + (q & 1);
        }
        int row = w * 128 + rt * 16 + (lane & 15);
        int k   = kt * 32 + ((lane >> 4) << 3) + jj;
        float v = (m == 0) ? W_hh1[row * 256 + k]
                : (m == 1) ? W_ih2[row * 256 + k]
                           : W_hh2[row * 256 + k];
        wh[e] = (_Float16)v;
    }
    for (int j = idx; j < 1024; j += stride) {
        wf[FS + j]        = W_ih1[j * 2 + 0];
        wf[FS + 1024 + j] = W_ih1[j * 2 + 1];
        wf[FS + 2048 + j] = b_ih1[j] + b_hh1[j];
        wf[FS + 3072 + j] = b_ih2[j] + b_hh2[j];
    }
}

__device__ __forceinline__ float sig_(float v) {
    return 1.f / (1.f + __expf(-v));
}
__device__ __forceinline__ float tanh_(float v) {
    return 1.f - 2.f / (__expf(2.f * v) + 1.f);
}
__device__ __forceinline__ v4f mfma16(vh8 a, vh8 b, v4f c) {
    return __builtin_amdgcn_mfma_f32_16x16x32_f16(a, b, c, 0, 0, 0);
}

// lgkm-only barrier: LDS drained, weight-stream vmem stays in flight.
#define BARRIER() __asm__ volatile("s_waitcnt lgkmcnt(0)\ns_barrier" ::: "memory")

__global__ __launch_bounds__(NT, 2) void lstm_kernel(
    const float* __restrict__ x,      // (512, 256, 2)
    const void* __restrict__ ws,
    const float* __restrict__ W_lin,  // (2, 256)
    const float* __restrict__ b_lin,  // (2,)
    float* __restrict__ out)          // (512, 256, 2)
{
    __shared__ float g1buf[2][1024];               // raw Whh1*h1 [batch][row]
    __shared__ float g2buf[2][1024];               // gates2 gemm (partial/final)
    __shared__ __align__(16) _Float16 h1s[2][256]; // h1 [batch][unit]
    __shared__ __align__(16) _Float16 h2s[2][256]; // h2
    __shared__ __align__(16) char lds_park[NLPF * 8 * FRB]; // 128 KB

    const int tid = threadIdx.x;
    const int lane = tid & 63, w = tid >> 6;       // wave id = rowgroup
    const int u = tid & 255, bu = tid >> 8;        // cell-update: unit, batch
    const int b0 = blockIdx.x * 2;
    const char* wstream = (const char*)ws;
    const float* wf = (const float*)ws;
    const int l16 = lane * 16;

    // U-stage affine constants: rows u, 256+u, 512+u, 768+u
    float wxa[4], wxb[4], b1c[4], b2c[4];
    #pragma unroll
    for (int g = 0; g < 4; ++g) {
        int r = g * 256 + u;
        wxa[g] = wf[FS + r];        wxb[g] = wf[FS + 1024 + r];
        b1c[g] = wf[FS + 2048 + r]; b2c[g] = wf[FS + 3072 + r];
    }

    // y-head: waves 0..3 -> (batch ob, output oo); lane covers 4 units
    const int ob = (w >> 1) & 1, oo = w & 1;
    const float wl0 = W_lin[oo * 256 + 4 * lane + 0];
    const float wl1 = W_lin[oo * 256 + 4 * lane + 1];
    const float wl2 = W_lin[oo * 256 + 4 * lane + 2];
    const float wl3 = W_lin[oo * 256 + 4 * lane + 3];
    const float blin = b_lin[oo];

    // zero initial h and g1buf (t=0: Whh1*h1(-1) = 0)
    ((_Float16*)h1s)[tid] = (_Float16)0.f;
    ((_Float16*)h2s)[tid] = (_Float16)0.f;
    g1buf[0][tid] = 0.f; g1buf[0][512 + tid] = 0.f;
    g1buf[1][tid] = 0.f; g1buf[1][512 + tid] = 0.f;

    float c1 = 0.f, c2 = 0.f;

    // stage LDS parks: lds[(q*8+w)*1024 + l16] <- ws[LPBASE+(w*16+q)*1024+l16]
    for (int q = 0; q < NLPF; ++q) {
        *(vh8*)&lds_park[(((q << 3) + w) << 10) + l16] =
            *(const vh8*)(wstream + LPBASE + (((w << 4) + q) << 10) + l16);
    }

    // VGPR parks: 32 frags (Whh2 ktiles 1..4 x 8 rowtiles), PINNED.
    vh8 wreg[NVPF];
    #pragma unroll
    for (int p = 0; p < NVPF; ++p) {
        union { vh8 v; float f[4]; } tpk;
        tpk.v = *(const vh8*)(wstream + VPBASE + ((w * NVPF + p) << 10) + l16);
        asm volatile("" : "+v"(tpk.f[0]), "+v"(tpk.f[1]),
                          "+v"(tpk.f[2]), "+v"(tpk.f[3]));
        wreg[p] = tpk.v;
    }

    // single stream: per-wave base, 8 named rotating buffers, uniform sp.
    // Invariant: consumption c (0..143 per step) uses slot c&7 == frag c.
    const char* wbase = wstream + (size_t)w * (NSF * FRB);
    int sp = 0;
    vh8 B0, B1, B2, B3, B4, B5, B6, B7;
    auto LDA = [&](vh8& d) {
        d = *(const vh8*)(wbase + sp + l16);
        sp += FRB; if (sp == NSF * FRB) sp = 0;
    };
    LDA(B0); LDA(B1); LDA(B2); LDA(B3);
    LDA(B4); LDA(B5); LDA(B6); LDA(B7);

    // B-fragment from h LDS: col=lane&15 (only 0/1 real; garbage cols read
    // batch lane&1 - finite, discarded). k = kt*32 + (lane>>4)*8 .. +7.
    auto bfrag = [&](const _Float16 (*hp)[256], int kt) -> vh8 {
        return *(const vh8*)&hp[lane & 1][kt * 32 + ((lane >> 4) << 3)];
    };

    const int bx = b0 + bu;
    vf2 xv = *(const vf2*)(x + (size_t)bx * 512);   // x(0)

    __syncthreads();   // init barrier (full drain once is fine)

    #pragma unroll 1
    for (int t = 0; t < TSTEPS; ++t) {
        // ---- U1: gates1(t) = g1buf(raw) + b1 + Wih1*x(t) -> h1(t) ----
        {
            float p0 = g1buf[bu][u]       + b1c[0] + wxa[0] * xv.x + wxb[0] * xv.y;
            float p1 = g1buf[bu][256 + u] + b1c[1] + wxa[1] * xv.x + wxb[1] * xv.y;
            float p2 = g1buf[bu][512 + u] + b1c[2] + wxa[2] * xv.x + wxb[2] * xv.y;
            float p3 = g1buf[bu][768 + u] + b1c[3] + wxa[3] * xv.x + wxb[3] * xv.y;
            c1 = sig_(p1) * c1 + sig_(p0) * tanh_(p2);
            h1s[bu][u] = (_Float16)(sig_(p3) * tanh_(c1));
        }
        {   // prefetch x(t+1) (wraps harmlessly)
            const int tn = (t + 1) & (TSTEPS - 1);
            xv = *(const vf2*)(x + (size_t)bx * 512 + tn * 2);
        }
        BARRIER();   // B1: h1(t) visible; h2(t-1) (from prev U2) visible

        // ---- y(t-1) (deferred; h2(t-1) stable in this epoch) ----
        if (t > 0 && w < 4) {
            vh4 hv = *(const vh4*)&h2s[ob][4 * lane];
            float s = (float)hv.x * wl0 + (float)hv.y * wl1
                    + (float)hv.z * wl2 + (float)hv.w * wl3;
            #pragma unroll
            for (int m = 32; m >= 1; m >>= 1) s += __shfl_xor(s, m, 64);
            if (lane == 0)
                out[(size_t)(b0 + ob) * 512 + (t - 1) * 2 + oo] = s + blin;
        }

        // ---- gates1(t+1) raw = Whh1 * h1(t)  [consumptions 0..63] ----
        #pragma unroll 1
        for (int rt = 0; rt < 8; ++rt) {
            v4f acc = {0.f, 0.f, 0.f, 0.f};
            acc = mfma16(B0, bfrag(h1s, 0), acc); LDA(B0);
            acc = mfma16(B1, bfrag(h1s, 1), acc); LDA(B1);
            acc = mfma16(B2, bfrag(h1s, 2), acc); LDA(B2);
            acc = mfma16(B3, bfrag(h1s, 3), acc); LDA(B3);
            acc = mfma16(B4, bfrag(h1s, 4), acc); LDA(B4);
            acc = mfma16(B5, bfrag(h1s, 5), acc); LDA(B5);
            acc = mfma16(B6, bfrag(h1s, 6), acc); LDA(B6);
            acc = mfma16(B7, bfrag(h1s, 7), acc); LDA(B7);
            if ((lane & 15) < 2)
                *(v4f*)&g1buf[lane & 15][w * 128 + rt * 16 + ((lane >> 4) << 2)] = acc;
        }

        // ---- gates2 pass 2a: partial = Wih2 * h1(t)  [cons. 64..127] ----
        #pragma unroll 1
        for (int rt = 0; rt < 8; ++rt) {
            v4f acc = {0.f, 0.f, 0.f, 0.f};
            acc = mfma16(B0, bfrag(h1s, 0), acc); LDA(B0);
            acc = mfma16(B1, bfrag(h1s, 1), acc); LDA(B1);
            acc = mfma16(B2, bfrag(h1s, 2), acc); LDA(B2);
            acc = mfma16(B3, bfrag(h1s, 3), acc); LDA(B3);
            acc = mfma16(B4, bfrag(h1s, 4), acc); LDA(B4);
            acc = mfma16(B5, bfrag(h1s, 5), acc); LDA(B5);
            acc = mfma16(B6, bfrag(h1s, 6), acc); LDA(B6);
            acc = mfma16(B7, bfrag(h1s, 7), acc); LDA(B7);
            if ((lane & 15) < 2)
                *(v4f*)&g2buf[lane & 15][w * 128 + rt * 16 + ((lane >> 4) << 2)] = acc;
        }

        // ---- gates2 pass 2b: += Whh2 * h2(t-1)  [cons. 128..143 = 8 x
        //      (kt0, kt5) streamed pairs; kt1..4 VGPR parks (static idx);
        //      kt6..7 LDS parks]. Port stays fed (16KB/wave this phase);
        //      refills wrap into next step's frags 0..15. ----
#define P2B(RT, BA, BB)                                                        \
        {                                                                      \
            v4f acc = {0.f, 0.f, 0.f, 0.f};                                    \
            if ((lane & 15) < 2)                                               \
                acc = *(const v4f*)&g2buf[lane & 15]                           \
                        [w * 128 + RT * 16 + ((lane >> 4) << 2)];              \
            acc = mfma16(BA, bfrag(h2s, 0), acc); LDA(BA);                     \
            acc = mfma16(wreg[RT * 4 + 0], bfrag(h2s, 1), acc);                \
            acc = mfma16(wreg[RT * 4 + 1], bfrag(h2s, 2), acc);                \
            acc = mfma16(wreg[RT * 4 + 2], bfrag(h2s, 3), acc);                \
            acc = mfma16(wreg[RT * 4 + 3], bfrag(h2s, 4), acc);                \
            acc = mfma16(BB, bfrag(h2s, 5), acc); LDA(BB);                     \
            {                                                                  \
                vh8 A6 = *(const vh8*)                                         \
                    &lds_park[((((RT * 2 + 0) << 3) + w) << 10) + l16];        \
                acc = mfma16(A6, bfrag(h2s, 6), acc);                          \
            }                                                                  \
            {                                                                  \
                vh8 A7 = *(const vh8*)                                         \
                    &lds_park[((((RT * 2 + 1) << 3) + w) << 10) + l16];        \
                acc = mfma16(A7, bfrag(h2s, 7), acc);                          \
            }                                                                  \
            if ((lane & 15) < 2)                                               \
                *(v4f*)&g2buf[lane & 15]                                       \
                    [w * 128 + RT * 16 + ((lane >> 4) << 2)] = acc;            \
        }
        P2B(0, B0, B1) P2B(1, B2, B3) P2B(2, B4, B5) P2B(3, B6, B7)
        P2B(4, B0, B1) P2B(5, B2, B3) P2B(6, B4, B5) P2B(7, B6, B7)
#undef P2B
        BARRIER();   // B2: g1buf/g2buf visible

        // ---- U2: gates2 + b2 -> h2(t) ----
        {
            float q0 = g2buf[bu][u]       + b2c[0];
            float q1 = g2buf[bu][256 + u] + b2c[1];
            float q2 = g2buf[bu][512 + u] + b2c[2];
            float q3 = g2buf[bu][768 + u] + b2c[3];
            c2 = sig_(q1) * c2 + sig_(q0) * tanh_(q2);
            h2s[bu][u] = (_Float16)(sig_(q3) * tanh_(c2));
        }
        // no barrier: next iteration's B1 publishes h2(t) before it's read
    }

    // ---- tail: y(255) ----
    BARRIER();
    if (w < 4) {
        vh4 hv = *(const vh4*)&h2s[ob][4 * lane];
        float s = (float)hv.x * wl0 + (float)hv.y * wl1
                + (float)hv.z * wl2 + (float)hv.w * wl3;
        #pragma unroll
        for (int m = 32; m >= 1; m >>= 1) s += __shfl_xor(s, m, 64);
        if (lane == 0)
            out[(size_t)(b0 + ob) * 512 + 255 * 2 + oo] = s + blin;
    }
}

extern "C" void kernel_launch(void* const* d_in, const int* in_sizes, int n_in,
                              void* d_out, int out_size, void* d_ws, size_t ws_size,
                              hipStream_t stream) {
    const float* x     = (const float*)d_in[0];
    const float* W_ih1 = (const float*)d_in[1];
    const float* W_hh1 = (const float*)d_in[2];
    const float* b_ih1 = (const float*)d_in[3];
    const float* b_hh1 = (const float*)d_in[4];
    const float* W_ih2 = (const float*)d_in[5];
    const float* W_hh2 = (const float*)d_in[6];
    const float* b_ih2 = (const float*)d_in[7];
    const float* b_hh2 = (const float*)d_in[8];
    const float* W_lin = (const float*)d_in[9];
    const float* b_lin = (const float*)d_in[10];
    float* out = (float*)d_out;

    prep_kernel<<<256, 256, 0, stream>>>(W_ih1, W_hh1, b_ih1, b_hh1,
                                         W_ih2, W_hh2, b_ih2, b_hh2, d_ws);
    lstm_kernel<<<256, NT, 0, stream>>>(x, d_ws, W_lin, b_lin, out);
}